// Round 11
// baseline (994.308 us; speedup 1.0000x reference)
//
#include <hip/hip_runtime.h>

// MSDeformAttn pixel decoder. v10: GEMM+LN fusion with 512-thread blocks
// (8 waves -> fixes round-6's 4-wave occupancy failure), deform reverted to
// v8 form. bf16 residual stream throughout.
// D=256, NH=8, DH=32, NL=3, NP=4, DFF=1024, B=4, Q=5376, M=B*Q=21504.

#define DMODEL 256
#define NLAYERS 6
#define BATCH 4
#define QTOT 5376
#define MROWS (BATCH * QTOT)   // 21504 = 168*128 = 336*64

typedef __bf16 bf16x8 __attribute__((ext_vector_type(8)));
typedef __bf16 bf16x4 __attribute__((ext_vector_type(4)));
typedef float floatx4 __attribute__((ext_vector_type(4)));

#define GLOAD(gp, lp)                                                          \
  __builtin_amdgcn_global_load_lds(                                            \
      (__attribute__((address_space(1))) void*)(gp),                           \
      (__attribute__((address_space(3))) void*)(lp), 16, 0, 0)

// ---------------------------------------------------------------------------
// Flatten via LDS tile transpose. Writes xb, posb, qb (all bf16).
// ---------------------------------------------------------------------------
__global__ __launch_bounds__(256) void flatten_kernel(
    const float* __restrict__ s0, const float* __restrict__ p0,
    const float* __restrict__ s1, const float* __restrict__ p1,
    const float* __restrict__ s2, const float* __restrict__ p2,
    const float* __restrict__ lvl, __bf16* __restrict__ xb,
    __bf16* __restrict__ posb, __bf16* __restrict__ qb) {
  __shared__ float ls[32][33];
  __shared__ float lp[32][33];
  int b = blockIdx.y;
  int tile = blockIdx.x;
  const float* sp; const float* pp; int l, hw, tp, td, qbase;
  if (tile < 1024)      { l = 0; hw = 4096; int t = tile;        td = t & 7; tp = t >> 3; qbase = 0; sp = s0; pp = p0; }
  else if (tile < 1280) { l = 1; hw = 1024; int t = tile - 1024; td = t & 7; tp = t >> 3; qbase = 4096; sp = s1; pp = p1; }
  else                  { l = 2; hw = 256;  int t = tile - 1280; td = t & 7; tp = t >> 3; qbase = 5120; sp = s2; pp = p2; }
  int tx = threadIdx.x & 31, ty = threadIdx.x >> 5;
  int d0 = td * 32, pbase = tp * 32;
#pragma unroll
  for (int r = 0; r < 4; ++r) {
    int dl = r * 8 + ty;
    size_t gi = ((size_t)(b * DMODEL + d0 + dl)) * hw + pbase + tx;
    ls[dl][tx] = sp[gi];
    lp[dl][tx] = pp[gi];
  }
  __syncthreads();
  int d = d0 + tx;
  float lv = lvl[l * DMODEL + d];
#pragma unroll
  for (int r = 0; r < 4; ++r) {
    int pl = r * 8 + ty;
    size_t bq = (size_t)b * QTOT + qbase + pbase + pl;
    float xv = ls[tx][pl];
    float pv = lp[tx][pl] + lv;
    xb[bq * DMODEL + d]   = (__bf16)xv;
    posb[bq * DMODEL + d] = (__bf16)pv;
    qb[bq * DMODEL + d]   = (__bf16)(xv + pv);
  }
}

// ---------------------------------------------------------------------------
// Coalesced transpose pack: W [L][K][N] fp32 -> Wt [L][N][K] bf16.
// ---------------------------------------------------------------------------
__global__ __launch_bounds__(256) void pack_t_kernel(
    const float* __restrict__ W, __bf16* __restrict__ Wt, int K, int N) {
  __shared__ float ls[32][33];
  int l = blockIdx.z;
  int n0 = blockIdx.x * 32, k0 = blockIdx.y * 32;
  int tx = threadIdx.x & 31, ty = threadIdx.x >> 5;
  const float* src = W + (size_t)l * K * N;
#pragma unroll
  for (int r = 0; r < 4; ++r)
    ls[ty + r * 8][tx] = src[(size_t)(k0 + ty + r * 8) * N + n0 + tx];
  __syncthreads();
  __bf16* dst = Wt + (size_t)l * N * K;
#pragma unroll
  for (int r = 0; r < 4; ++r)
    dst[(size_t)(n0 + ty + r * 8) * K + k0 + tx] = (__bf16)ls[tx][ty + r * 8];
}

// Combined [W_off|W_attn|pad|W_val] coalesced transpose -> Wt [L][640][256]
__global__ __launch_bounds__(256) void pack_qv_t_kernel(
    const float* __restrict__ Woff, const float* __restrict__ Wattn,
    const float* __restrict__ Wval, __bf16* __restrict__ Wt) {
  __shared__ float ls[32][33];
  int l = blockIdx.z;
  int tc = blockIdx.x, k0 = blockIdx.y * 32;
  int tx = threadIdx.x & 31, ty = threadIdx.x >> 5;
  const float* src; int n0, sn;
  if (tc < 6)       { src = Woff  + (size_t)l * 256 * 192; n0 = tc * 32;        sn = 192; }
  else if (tc < 9)  { src = Wattn + (size_t)l * 256 * 96;  n0 = (tc - 6) * 32;  sn = 96;  }
  else if (tc < 12) { src = nullptr; n0 = 0; sn = 0; }
  else              { src = Wval  + (size_t)l * 256 * 256; n0 = (tc - 12) * 32; sn = 256; }
#pragma unroll
  for (int r = 0; r < 4; ++r)
    ls[ty + r * 8][tx] = src ? src[(size_t)(k0 + ty + r * 8) * sn + n0 + tx] : 0.f;
  __syncthreads();
  __bf16* dst = Wt + (size_t)l * 640 * 256 + (size_t)tc * 32 * 256;
#pragma unroll
  for (int r = 0; r < 4; ++r)
    dst[(size_t)(ty + r * 8) * 256 + k0 + tx] = (__bf16)ls[tx][ty + r * 8];
}

__global__ __launch_bounds__(640) void pack_bias_kernel(
    const float* __restrict__ boff, const float* __restrict__ battn,
    const float* __restrict__ bval, float* __restrict__ bc) {
  int l = blockIdx.x, n = threadIdx.x;
  float b = 0.f;
  if (n < 192)       b = boff[l * 192 + n];
  else if (n < 288)  b = battn[l * 96 + (n - 192)];
  else if (n >= 384) b = bval[l * 256 + (n - 384)];
  bc[l * 640 + n] = b;
}

// ---------------------------------------------------------------------------
// 128x128 MFMA core (BK=32, 4 waves 2x2).
// ---------------------------------------------------------------------------
#define GEMM_CORE(A_, B_, K_)                                                  \
  for (int k0 = 0; k0 < (K_); k0 += 32) {                                      \
    __syncthreads();                                                           \
    _Pragma("unroll")                                                          \
    for (int cc = 0; cc < 2; ++cc) {                                           \
      int c = wid * 2 + cc;                                                    \
      GLOAD((A_) + (size_t)c * 16 * (K_) + k0, As + c * 512);                  \
      GLOAD((B_) + (size_t)c * 16 * (K_) + k0, Bs + c * 512);                  \
    }                                                                          \
    __syncthreads();                                                           \
    bf16x8 af[4], bfr[4];                                                      \
    _Pragma("unroll")                                                          \
    for (int i = 0; i < 4; ++i)                                                \
      af[i] = *(const bf16x8*)&As[(wr * 64 + i * 16 + (lane & 15)) * 32 + (lane >> 4) * 8]; \
    _Pragma("unroll")                                                          \
    for (int j = 0; j < 4; ++j)                                                \
      bfr[j] = *(const bf16x8*)&Bs[(wc * 64 + j * 16 + (lane & 15)) * 32 + (lane >> 4) * 8]; \
    _Pragma("unroll")                                                          \
    for (int i = 0; i < 4; ++i)                                                \
      _Pragma("unroll")                                                        \
      for (int j = 0; j < 4; ++j)                                              \
        acc[i][j] = __builtin_amdgcn_mfma_f32_16x16x32_bf16(af[i], bfr[j], acc[i][j], 0, 0, 0); \
  }

// ---------------------------------------------------------------------------
// Generic bf16 GEMM (128x128): used for ff1.
// ---------------------------------------------------------------------------
template<int RELU, int BF16OUT>
__global__ __launch_bounds__(256) void gemm_bf16_kernel(
    const __bf16* __restrict__ A, const __bf16* __restrict__ Wt,
    const float* __restrict__ bias, float* __restrict__ C,
    __bf16* __restrict__ Cb, int N, int K) {
  __shared__ __bf16 As[128 * 32];
  __shared__ __bf16 Bs[128 * 32];
  int t = threadIdx.x;
  int lane = t & 63, wid = t >> 6;
  int wr = wid >> 1, wc = wid & 1;
  int row0 = blockIdx.y * 128;
  int n0 = blockIdx.x * 128;
  floatx4 acc[4][4] = {};
  int srow = lane >> 2;
  int skoff = (lane & 3) * 8;
  const __bf16* Abase = A + (size_t)(row0 + srow) * K + skoff;
  const __bf16* Bbase = Wt + (size_t)(n0 + srow) * K + skoff;
  GEMM_CORE(Abase, Bbase, K)
  int orow = row0 + wr * 64 + (lane >> 4) * 4;
  int ocol = n0 + wc * 64 + (lane & 15);
#pragma unroll
  for (int i = 0; i < 4; ++i)
#pragma unroll
    for (int j = 0; j < 4; ++j) {
      int col = ocol + j * 16;
      float bv = bias[col];
#pragma unroll
      for (int r = 0; r < 4; ++r) {
        int row = orow + i * 16 + r;
        float v = acc[i][j][r] + bv;
        if (RELU) v = fmaxf(v, 0.f);
        if (BF16OUT) Cb[(size_t)row * N + col] = (__bf16)v;
        else         C[(size_t)row * N + col] = v;
      }
    }
}

// ---------------------------------------------------------------------------
// Fused [qproj|val] GEMM (128x128): bn<3 -> qproj fp32 (stride 384),
//                                    bn>=3 -> val bf16 (stride 256)
// ---------------------------------------------------------------------------
__global__ __launch_bounds__(256) void gemm_qv_kernel(
    const __bf16* __restrict__ qb, const __bf16* __restrict__ xb,
    const __bf16* __restrict__ Wt, const float* __restrict__ bias,
    float* __restrict__ qproj, __bf16* __restrict__ valb) {
  __shared__ __bf16 As[128 * 32];
  __shared__ __bf16 Bs[128 * 32];
  int t = threadIdx.x;
  int lane = t & 63, wid = t >> 6;
  int wr = wid >> 1, wc = wid & 1;
  int bn = blockIdx.x;                    // 0..4
  int row0 = blockIdx.y * 128;
  int n0 = bn * 128;
  const __bf16* A = (bn < 3) ? qb : xb;
  floatx4 acc[4][4] = {};
  int srow = lane >> 2;
  int skoff = (lane & 3) * 8;
  const __bf16* Abase = A + (size_t)(row0 + srow) * 256 + skoff;
  const __bf16* Bbase = Wt + (size_t)(n0 + srow) * 256 + skoff;
  GEMM_CORE(Abase, Bbase, 256)
  int orow = row0 + wr * 64 + (lane >> 4) * 4;
  int ocol = wc * 64 + (lane & 15);
#pragma unroll
  for (int i = 0; i < 4; ++i)
#pragma unroll
    for (int j = 0; j < 4; ++j) {
      int col = ocol + j * 16;
      float bv = bias[n0 + col];
#pragma unroll
      for (int r = 0; r < 4; ++r) {
        int row = orow + i * 16 + r;
        float v = acc[i][j][r] + bv;
        if (bn < 3) qproj[(size_t)row * 384 + n0 + col] = v;
        else        valb[(size_t)row * 256 + (n0 - 384) + col] = (__bf16)v;
      }
    }
}

// ---------------------------------------------------------------------------
// Fused GEMM + residual + LayerNorm, 512 threads (8 waves, 2x4).
// BM=64, BN=256 (full row per block -> LN feasible), BK=32.
// out = LN(xin + A@Wt^T + bias); writes xout bf16, opt qb=bf16(out+posb),
// opt fout fp32. Grid: MROWS/64 = 336 blocks, 10.5 waves/CU.
// ---------------------------------------------------------------------------
template<int QB, int KK>
__global__ __launch_bounds__(512) void gemm_ln512_kernel(
    const __bf16* __restrict__ A, const __bf16* __restrict__ Wt,
    const float* __restrict__ bias, const __bf16* __restrict__ xin,
    const float* __restrict__ g, const float* __restrict__ bta,
    __bf16* __restrict__ xout, const __bf16* __restrict__ posb,
    __bf16* __restrict__ qb, float* __restrict__ fout) {
  __shared__ __bf16 As[64 * 32];     // 4 KB
  __shared__ __bf16 Bs[256 * 32];    // 16 KB
  __shared__ float part[4][64][2];   // 2 KB: per-col-wave row partials
  __shared__ float stats[64][2];
  int t = threadIdx.x, lane = t & 63, wid = t >> 6;   // 8 waves
  int wr = wid >> 2, wc = wid & 3;                    // 2 x 4
  int row0 = blockIdx.x * 64;
  floatx4 acc[2][4] = {};
  int srow = lane >> 2, skoff = (lane & 3) * 8;
  const __bf16* Abase = A + (size_t)(row0 + srow) * KK + skoff;
  const __bf16* Bbase = Wt + (size_t)srow * KK + skoff;

  for (int k0 = 0; k0 < KK; k0 += 32) {
    __syncthreads();
    // 20 chunks of 16 rows: 0..3 -> A(64), 4..19 -> B(256); interleaved over 8 waves
#pragma unroll
    for (int cc = 0; cc < 3; ++cc) {
      int c = cc * 8 + wid;                 // 0..23
      if (c < 4)       GLOAD(Abase + (size_t)c * 16 * KK + k0, As + c * 512);
      else if (c < 20) GLOAD(Bbase + (size_t)(c - 4) * 16 * KK + k0, Bs + (c - 4) * 512);
    }
    __syncthreads();
    bf16x8 af[2], bfr[4];
#pragma unroll
    for (int i = 0; i < 2; ++i)
      af[i] = *(const bf16x8*)&As[(wr * 32 + i * 16 + (lane & 15)) * 32 + (lane >> 4) * 8];
#pragma unroll
    for (int j = 0; j < 4; ++j)
      bfr[j] = *(const bf16x8*)&Bs[(wc * 64 + j * 16 + (lane & 15)) * 32 + (lane >> 4) * 8];
#pragma unroll
    for (int i = 0; i < 2; ++i)
#pragma unroll
      for (int j = 0; j < 4; ++j)
        acc[i][j] = __builtin_amdgcn_mfma_f32_16x16x32_bf16(af[i], bfr[j], acc[i][j], 0, 0, 0);
  }

  // Epilogue: v = acc + bias + xin; per-row sums across this wave's 64 cols
  int g4 = (lane >> 4) * 4;
  int m = lane & 15;
  float psum[2][4] = {}, psq[2][4] = {};
#pragma unroll
  for (int i = 0; i < 2; ++i)
#pragma unroll
    for (int j = 0; j < 4; ++j) {
      int col = wc * 64 + m + j * 16;
      float bv = bias[col];
#pragma unroll
      for (int r = 0; r < 4; ++r) {
        int lr = wr * 32 + i * 16 + g4 + r;
        float v = acc[i][j][r] + bv + (float)xin[(size_t)(row0 + lr) * DMODEL + col];
        acc[i][j][r] = v;
        psum[i][r] += v;
        psq[i][r]  += v * v;
      }
    }
  // reduce across the 16 m-lanes (same g-group -> same rows)
#pragma unroll
  for (int o = 1; o < 16; o <<= 1)
#pragma unroll
    for (int i = 0; i < 2; ++i)
#pragma unroll
      for (int r = 0; r < 4; ++r) {
        psum[i][r] += __shfl_xor(psum[i][r], o);
        psq[i][r]  += __shfl_xor(psq[i][r], o);
      }
  if (m < 8) {
    int i = m >> 2, r = m & 3;
    int lr = wr * 32 + i * 16 + g4 + r;
    part[wc][lr][0] = psum[i][r];
    part[wc][lr][1] = psq[i][r];
  }
  __syncthreads();
  if (t < 64) {
    float s = part[0][t][0] + part[1][t][0] + part[2][t][0] + part[3][t][0];
    float q = part[0][t][1] + part[1][t][1] + part[2][t][1] + part[3][t][1];
    float mean = s * (1.f / 256.f);
    float var = q * (1.f / 256.f) - mean * mean;
    stats[t][0] = mean;
    stats[t][1] = rsqrtf(var + 1e-5f);
  }
  __syncthreads();
#pragma unroll
  for (int i = 0; i < 2; ++i)
#pragma unroll
    for (int j = 0; j < 4; ++j) {
      int col = wc * 64 + m + j * 16;
      float gv = g[col], bv = bta[col];
#pragma unroll
      for (int r = 0; r < 4; ++r) {
        int lr = wr * 32 + i * 16 + g4 + r;
        float mean = stats[lr][0], rstd = stats[lr][1];
        float o = (acc[i][j][r] - mean) * rstd * gv + bv;
        size_t idx = (size_t)(row0 + lr) * DMODEL + col;
        xout[idx] = (__bf16)o;
        if (QB) qb[idx] = (__bf16)(o + (float)posb[idx]);
        if (fout) fout[idx] = o;
      }
    }
}

// ---------------------------------------------------------------------------
// Deformable sampling + per-head softmax (v8 form). 32 threads/query,
// branchless clamped gathers (4x16B per point). Output bf16.
// ---------------------------------------------------------------------------
__global__ __launch_bounds__(256) void deform_kernel(
    const __bf16* __restrict__ val, const float* __restrict__ qproj,
    __bf16* __restrict__ out) {
  int bq = blockIdx.x * 8 + (threadIdx.x >> 5);
  int b = bq / QTOT, q = bq % QTOT;
  int tq = threadIdx.x & 31;
  int hid = tq >> 2, dq = (tq & 3) * 8;

  int p, wsrc;
  if (q < 4096)      { p = q;        wsrc = 64; }
  else if (q < 5120) { p = q - 4096; wsrc = 32; }
  else               { p = q - 5120; wsrc = 16; }
  float inv = 1.0f / (float)wsrc;
  float refx = ((float)(p % wsrc) + 0.5f) * inv;
  float refy = ((float)(p / wsrc) + 0.5f) * inv;

  const float* base = qproj + (size_t)bq * 384;
  float aw[12], ob[24];
  *(float4*)&aw[0] = *(const float4*)(base + 192 + hid * 12);
  *(float4*)&aw[4] = *(const float4*)(base + 192 + hid * 12 + 4);
  *(float4*)&aw[8] = *(const float4*)(base + 192 + hid * 12 + 8);
#pragma unroll
  for (int i = 0; i < 6; ++i)
    *(float4*)&ob[i * 4] = *(const float4*)(base + hid * 24 + i * 4);

  float mx = -1e30f;
#pragma unroll
  for (int k = 0; k < 12; ++k) mx = fmaxf(mx, aw[k]);
  float s = 0.f;
#pragma unroll
  for (int k = 0; k < 12; ++k) { aw[k] = __expf(aw[k] - mx); s += aw[k]; }
  float invs = 1.0f / s;
#pragma unroll
  for (int k = 0; k < 12; ++k) aw[k] *= invs;

  const __bf16* vb = val + ((size_t)b * QTOT) * DMODEL + hid * 32 + dq;

  const int starts[3] = {0, 4096, 5120};
  const int wls[3] = {64, 32, 16};
  float acc[8] = {};
#pragma unroll
  for (int l = 0; l < 3; ++l) {
    int wl = wls[l];
    float fwl = (float)wl;
    const __bf16* vlb = vb + (size_t)starts[l] * DMODEL;
#pragma unroll
    for (int pp = 0; pp < 4; ++pp) {
      float awp = aw[l * 4 + pp];
      float fx = refx * fwl + ob[(l * 4 + pp) * 2 + 0] - 0.5f;
      float fy = refy * fwl + ob[(l * 4 + pp) * 2 + 1] - 0.5f;
      float x0f = floorf(fx), y0f = floorf(fy);
      float lx = fx - x0f, ly = fy - y0f;
      int x0 = (int)x0f, y0 = (int)y0f;
      float wx0 = ((unsigned)x0 < (unsigned)wl) ? (1.f - lx) : 0.f;
      float wx1 = ((unsigned)(x0 + 1) < (unsigned)wl) ? lx : 0.f;
      float wy0 = (((unsigned)y0 < (unsigned)wl) ? (1.f - ly) : 0.f) * awp;
      float wy1 = (((unsigned)(y0 + 1) < (unsigned)wl) ? ly : 0.f) * awp;
      int xc0 = min(max(x0, 0), wl - 1);
      int xc1 = min(max(x0 + 1, 0), wl - 1);
      int yc0 = min(max(y0, 0), wl - 1);
      int yc1 = min(max(y0 + 1, 0), wl - 1);
      const __bf16* r0 = vlb + (size_t)(yc0 * wl) * DMODEL;
      const __bf16* r1 = vlb + (size_t)(yc1 * wl) * DMODEL;
      bf16x8 v00 = *(const bf16x8*)(r0 + (size_t)xc0 * DMODEL);
      bf16x8 v01 = *(const bf16x8*)(r0 + (size_t)xc1 * DMODEL);
      bf16x8 v10 = *(const bf16x8*)(r1 + (size_t)xc0 * DMODEL);
      bf16x8 v11 = *(const bf16x8*)(r1 + (size_t)xc1 * DMODEL);
      float w00 = wx0 * wy0, w01 = wx1 * wy0;
      float w10 = wx0 * wy1, w11 = wx1 * wy1;
#pragma unroll
      for (int e = 0; e < 8; ++e) {
        float v = w00 * (float)v00[e] + w01 * (float)v01[e] +
                  w10 * (float)v10[e] + w11 * (float)v11[e];
        acc[e] += v;
      }
    }
  }
  bf16x8 o;
#pragma unroll
  for (int e = 0; e < 8; ++e) o[e] = (__bf16)acc[e];
  *(bf16x8*)(out + (size_t)bq * DMODEL + hid * 32 + dq) = o;
}

// ---------------------------------------------------------------------------
extern "C" void kernel_launch(void* const* d_in, const int* in_sizes, int n_in,
                              void* d_out, int out_size, void* d_ws, size_t ws_size,
                              hipStream_t stream) {
  const float* src0 = (const float*)d_in[0];
  const float* pos0 = (const float*)d_in[1];
  const float* src1 = (const float*)d_in[2];
  const float* pos1 = (const float*)d_in[3];
  const float* src2 = (const float*)d_in[4];
  const float* pos2 = (const float*)d_in[5];
  const float* lvl  = (const float*)d_in[6];
  const float* W_off  = (const float*)d_in[7];
  const float* b_off  = (const float*)d_in[8];
  const float* W_attn = (const float*)d_in[9];
  const float* b_attn = (const float*)d_in[10];
  const float* W_val  = (const float*)d_in[11];
  const float* b_val  = (const float*)d_in[12];
  const float* W_out  = (const float*)d_in[13];
  const float* b_out  = (const float*)d_in[14];
  const float* ln1g = (const float*)d_in[15];
  const float* ln1b = (const float*)d_in[16];
  const float* W_ff1 = (const float*)d_in[17];
  const float* b_ff1 = (const float*)d_in[18];
  const float* W_ff2 = (const float*)d_in[19];
  const float* b_ff2 = (const float*)d_in[20];
  const float* ln2g = (const float*)d_in[21];
  const float* ln2b = (const float*)d_in[22];

  const size_t M = (size_t)MROWS;
  char* w = (char*)d_ws;
  __bf16* xb    = (__bf16*)w;                w += M * 256 * 2;
  __bf16* posb  = (__bf16*)w;                w += M * 256 * 2;
  __bf16* qb    = (__bf16*)w;                w += M * 256 * 2;   // alias: attn_bf
  float*  qproj = (float*)w;                 w += M * 384 * 4;
  __bf16* valb  = (__bf16*)w;                w += M * 256 * 2;
  __bf16* ffh   = (__bf16*)w;                w += M * 1024 * 2;
  __bf16* wqv_t = (__bf16*)w;                w += (size_t)NLAYERS * 640 * 256 * 2;
  __bf16* wout_t= (__bf16*)w;                w += (size_t)NLAYERS * 256 * 256 * 2;
  __bf16* wff1_t= (__bf16*)w;                w += (size_t)NLAYERS * 1024 * 256 * 2;
  __bf16* wff2_t= (__bf16*)w;                w += (size_t)NLAYERS * 256 * 1024 * 2;
  float*  bqv   = (float*)w;                 w += (size_t)NLAYERS * 640 * 4;
  __bf16* attn_bf = qb;

  pack_qv_t_kernel<<<dim3(20, 8, NLAYERS), 256, 0, stream>>>(W_off, W_attn, W_val, wqv_t);
  pack_bias_kernel<<<NLAYERS, 640, 0, stream>>>(b_off, b_attn, b_val, bqv);
  pack_t_kernel<<<dim3(8, 8, NLAYERS), 256, 0, stream>>>(W_out, wout_t, 256, 256);
  pack_t_kernel<<<dim3(32, 8, NLAYERS), 256, 0, stream>>>(W_ff1, wff1_t, 256, 1024);
  pack_t_kernel<<<dim3(8, 32, NLAYERS), 256, 0, stream>>>(W_ff2, wff2_t, 1024, 256);

  flatten_kernel<<<dim3(1344, BATCH), 256, 0, stream>>>(
      src0, pos0, src1, pos1, src2, pos2, lvl, xb, posb, qb);

  const int MT = MROWS / 128;   // 168
  const int LT = MROWS / 64;    // 336
  for (int i = 0; i < NLAYERS; ++i) {
    gemm_qv_kernel<<<dim3(5, MT), 256, 0, stream>>>(
        qb, xb, wqv_t + (size_t)i * 640 * 256, bqv + i * 640, qproj, valb);
    deform_kernel<<<MROWS / 8, 256, 0, stream>>>(valb, qproj, attn_bf);
    // x = LN1(x + attn @ W_out + b_out)   [fused, 512 threads]
    gemm_ln512_kernel<0, 256><<<LT, 512, 0, stream>>>(
        attn_bf, wout_t + (size_t)i * 256 * 256, b_out + i * 256,
        xb, ln1g + i * 256, ln1b + i * 256, xb, nullptr, nullptr, nullptr);
    // ffh = relu(x @ W_ff1 + b_ff1)
    gemm_bf16_kernel<1, 1><<<dim3(8, MT), 256, 0, stream>>>(
        xb, wff1_t + (size_t)i * 1024 * 256, b_ff1 + i * 1024, nullptr, ffh, 1024, 256);
    // x = LN2(x + ffh @ W_ff2 + b_ff2); qb = bf16(x + pos)  [fused]
    float* fout = (i == NLAYERS - 1) ? (float*)d_out : nullptr;
    gemm_ln512_kernel<1, 1024><<<LT, 512, 0, stream>>>(
        ffh, wff2_t + (size_t)i * 256 * 1024, b_ff2 + i * 256,
        xb, ln2g + i * 256, ln2b + i * 256, xb, posb, qb, fout);
  }
}

// Round 12
// 829.552 us; speedup vs baseline: 1.1986x; 1.1986x over previous
//
#include <hip/hip_runtime.h>

// MSDeformAttn pixel decoder. v11: = v8 (best, 840us) + 4x2 spatial tile
// deform block mapping (y-adjacent bilinear-corner reuse in L1) + merged
// weight-pack dispatches. LN fusion abandoned (failed 2x: occupancy/bank
// conflicts inherent to the epilogue structure).
// D=256, NH=8, DH=32, NL=3, NP=4, DFF=1024, B=4, Q=5376, M=B*Q=21504.

#define DMODEL 256
#define NLAYERS 6
#define BATCH 4
#define QTOT 5376
#define MROWS (BATCH * QTOT)   // 21504 = 168*128 = 336*64

typedef __bf16 bf16x8 __attribute__((ext_vector_type(8)));
typedef __bf16 bf16x4 __attribute__((ext_vector_type(4)));
typedef float floatx4 __attribute__((ext_vector_type(4)));

#define GLOAD(gp, lp)                                                          \
  __builtin_amdgcn_global_load_lds(                                            \
      (__attribute__((address_space(1))) void*)(gp),                           \
      (__attribute__((address_space(3))) void*)(lp), 16, 0, 0)

// ---------------------------------------------------------------------------
// Flatten via LDS tile transpose. Writes xb, posb, qb (all bf16).
// ---------------------------------------------------------------------------
__global__ __launch_bounds__(256) void flatten_kernel(
    const float* __restrict__ s0, const float* __restrict__ p0,
    const float* __restrict__ s1, const float* __restrict__ p1,
    const float* __restrict__ s2, const float* __restrict__ p2,
    const float* __restrict__ lvl, __bf16* __restrict__ xb,
    __bf16* __restrict__ posb, __bf16* __restrict__ qb) {
  __shared__ float ls[32][33];
  __shared__ float lp[32][33];
  int b = blockIdx.y;
  int tile = blockIdx.x;
  const float* sp; const float* pp; int l, hw, tp, td, qbase;
  if (tile < 1024)      { l = 0; hw = 4096; int t = tile;        td = t & 7; tp = t >> 3; qbase = 0; sp = s0; pp = p0; }
  else if (tile < 1280) { l = 1; hw = 1024; int t = tile - 1024; td = t & 7; tp = t >> 3; qbase = 4096; sp = s1; pp = p1; }
  else                  { l = 2; hw = 256;  int t = tile - 1280; td = t & 7; tp = t >> 3; qbase = 5120; sp = s2; pp = p2; }
  int tx = threadIdx.x & 31, ty = threadIdx.x >> 5;
  int d0 = td * 32, pbase = tp * 32;
#pragma unroll
  for (int r = 0; r < 4; ++r) {
    int dl = r * 8 + ty;
    size_t gi = ((size_t)(b * DMODEL + d0 + dl)) * hw + pbase + tx;
    ls[dl][tx] = sp[gi];
    lp[dl][tx] = pp[gi];
  }
  __syncthreads();
  int d = d0 + tx;
  float lv = lvl[l * DMODEL + d];
#pragma unroll
  for (int r = 0; r < 4; ++r) {
    int pl = r * 8 + ty;
    size_t bq = (size_t)b * QTOT + qbase + pbase + pl;
    float xv = ls[tx][pl];
    float pv = lp[tx][pl] + lv;
    xb[bq * DMODEL + d]   = (__bf16)xv;
    posb[bq * DMODEL + d] = (__bf16)pv;
    qb[bq * DMODEL + d]   = (__bf16)(xv + pv);
  }
}

// ---------------------------------------------------------------------------
// Merged coalesced transpose pack for W_out / W_ff1 / W_ff2 -> bf16 [N][K].
// Grid (576, NLAYERS): tt<64 -> W_out(256x256), tt<320 -> W_ff1(256x1024),
// else W_ff2(1024x256). 32x32 LDS tile each.
// ---------------------------------------------------------------------------
__global__ __launch_bounds__(256) void pack3_kernel(
    const float* __restrict__ Wout, const float* __restrict__ Wff1,
    const float* __restrict__ Wff2, __bf16* __restrict__ wout_t,
    __bf16* __restrict__ wff1_t, __bf16* __restrict__ wff2_t) {
  __shared__ float ls[32][33];
  int l = blockIdx.y;
  int tt = blockIdx.x;
  const float* src; __bf16* dst; int K, N, u, tilesx;
  if (tt < 64)       { src = Wout + (size_t)l * 256 * 256;  dst = wout_t + (size_t)l * 256 * 256;  K = 256;  N = 256;  u = tt;        tilesx = 8;  }
  else if (tt < 320) { src = Wff1 + (size_t)l * 256 * 1024; dst = wff1_t + (size_t)l * 1024 * 256; K = 256;  N = 1024; u = tt - 64;  tilesx = 32; }
  else               { src = Wff2 + (size_t)l * 1024 * 256; dst = wff2_t + (size_t)l * 256 * 1024; K = 1024; N = 256;  u = tt - 320; tilesx = 8;  }
  int n0 = (u % tilesx) * 32, k0 = (u / tilesx) * 32;
  int tx = threadIdx.x & 31, ty = threadIdx.x >> 5;
#pragma unroll
  for (int r = 0; r < 4; ++r)
    ls[ty + r * 8][tx] = src[(size_t)(k0 + ty + r * 8) * N + n0 + tx];
  __syncthreads();
#pragma unroll
  for (int r = 0; r < 4; ++r)
    dst[(size_t)(n0 + ty + r * 8) * K + k0 + tx] = (__bf16)ls[tx][ty + r * 8];
}

// Combined [W_off|W_attn|pad|W_val] coalesced transpose -> Wt [L][640][256]
__global__ __launch_bounds__(256) void pack_qv_t_kernel(
    const float* __restrict__ Woff, const float* __restrict__ Wattn,
    const float* __restrict__ Wval, __bf16* __restrict__ Wt) {
  __shared__ float ls[32][33];
  int l = blockIdx.z;
  int tc = blockIdx.x, k0 = blockIdx.y * 32;
  int tx = threadIdx.x & 31, ty = threadIdx.x >> 5;
  const float* src; int n0, sn;
  if (tc < 6)       { src = Woff  + (size_t)l * 256 * 192; n0 = tc * 32;        sn = 192; }
  else if (tc < 9)  { src = Wattn + (size_t)l * 256 * 96;  n0 = (tc - 6) * 32;  sn = 96;  }
  else if (tc < 12) { src = nullptr; n0 = 0; sn = 0; }
  else              { src = Wval  + (size_t)l * 256 * 256; n0 = (tc - 12) * 32; sn = 256; }
#pragma unroll
  for (int r = 0; r < 4; ++r)
    ls[ty + r * 8][tx] = src ? src[(size_t)(k0 + ty + r * 8) * sn + n0 + tx] : 0.f;
  __syncthreads();
  __bf16* dst = Wt + (size_t)l * 640 * 256 + (size_t)tc * 32 * 256;
#pragma unroll
  for (int r = 0; r < 4; ++r)
    dst[(size_t)(ty + r * 8) * 256 + k0 + tx] = (__bf16)ls[tx][ty + r * 8];
}

__global__ __launch_bounds__(640) void pack_bias_kernel(
    const float* __restrict__ boff, const float* __restrict__ battn,
    const float* __restrict__ bval, float* __restrict__ bc) {
  int l = blockIdx.x, n = threadIdx.x;
  float b = 0.f;
  if (n < 192)       b = boff[l * 192 + n];
  else if (n < 288)  b = battn[l * 96 + (n - 192)];
  else if (n >= 384) b = bval[l * 256 + (n - 384)];
  bc[l * 640 + n] = b;
}

// ---------------------------------------------------------------------------
// 128x128 MFMA core (BK=32, 4 waves 2x2).
// ---------------------------------------------------------------------------
#define GEMM_CORE(A_, B_, K_)                                                  \
  for (int k0 = 0; k0 < (K_); k0 += 32) {                                      \
    __syncthreads();                                                           \
    _Pragma("unroll")                                                          \
    for (int cc = 0; cc < 2; ++cc) {                                           \
      int c = wid * 2 + cc;                                                    \
      GLOAD((A_) + (size_t)c * 16 * (K_) + k0, As + c * 512);                  \
      GLOAD((B_) + (size_t)c * 16 * (K_) + k0, Bs + c * 512);                  \
    }                                                                          \
    __syncthreads();                                                           \
    bf16x8 af[4], bfr[4];                                                      \
    _Pragma("unroll")                                                          \
    for (int i = 0; i < 4; ++i)                                                \
      af[i] = *(const bf16x8*)&As[(wr * 64 + i * 16 + (lane & 15)) * 32 + (lane >> 4) * 8]; \
    _Pragma("unroll")                                                          \
    for (int j = 0; j < 4; ++j)                                                \
      bfr[j] = *(const bf16x8*)&Bs[(wc * 64 + j * 16 + (lane & 15)) * 32 + (lane >> 4) * 8]; \
    _Pragma("unroll")                                                          \
    for (int i = 0; i < 4; ++i)                                                \
      _Pragma("unroll")                                                        \
      for (int j = 0; j < 4; ++j)                                              \
        acc[i][j] = __builtin_amdgcn_mfma_f32_16x16x32_bf16(af[i], bfr[j], acc[i][j], 0, 0, 0); \
  }

// ---------------------------------------------------------------------------
// Generic bf16 GEMM (128x128): used for ff1.
// ---------------------------------------------------------------------------
template<int RELU, int BF16OUT>
__global__ __launch_bounds__(256) void gemm_bf16_kernel(
    const __bf16* __restrict__ A, const __bf16* __restrict__ Wt,
    const float* __restrict__ bias, float* __restrict__ C,
    __bf16* __restrict__ Cb, int N, int K) {
  __shared__ __bf16 As[128 * 32];
  __shared__ __bf16 Bs[128 * 32];
  int t = threadIdx.x;
  int lane = t & 63, wid = t >> 6;
  int wr = wid >> 1, wc = wid & 1;
  int row0 = blockIdx.y * 128;
  int n0 = blockIdx.x * 128;
  floatx4 acc[4][4] = {};
  int srow = lane >> 2;
  int skoff = (lane & 3) * 8;
  const __bf16* Abase = A + (size_t)(row0 + srow) * K + skoff;
  const __bf16* Bbase = Wt + (size_t)(n0 + srow) * K + skoff;
  GEMM_CORE(Abase, Bbase, K)
  int orow = row0 + wr * 64 + (lane >> 4) * 4;
  int ocol = n0 + wc * 64 + (lane & 15);
#pragma unroll
  for (int i = 0; i < 4; ++i)
#pragma unroll
    for (int j = 0; j < 4; ++j) {
      int col = ocol + j * 16;
      float bv = bias[col];
#pragma unroll
      for (int r = 0; r < 4; ++r) {
        int row = orow + i * 16 + r;
        float v = acc[i][j][r] + bv;
        if (RELU) v = fmaxf(v, 0.f);
        if (BF16OUT) Cb[(size_t)row * N + col] = (__bf16)v;
        else         C[(size_t)row * N + col] = v;
      }
    }
}

// ---------------------------------------------------------------------------
// BM=64 x BN=128 GEMM (BK=32, 4 waves 2x2, wave tile 32x64, acc[2][4]).
// For N=256 shapes (out-proj, ff2): 672 blocks.
// ---------------------------------------------------------------------------
template<int RELU>
__global__ __launch_bounds__(256) void gemm64_bf16_kernel(
    const __bf16* __restrict__ A, const __bf16* __restrict__ Wt,
    const float* __restrict__ bias, __bf16* __restrict__ Cb, int N, int K) {
  __shared__ __bf16 As[64 * 32];
  __shared__ __bf16 Bs[128 * 32];
  int t = threadIdx.x;
  int lane = t & 63, wid = t >> 6;
  int wr = wid >> 1, wc = wid & 1;
  int row0 = blockIdx.y * 64;
  int n0 = blockIdx.x * 128;
  floatx4 acc[2][4] = {};
  int srow = lane >> 2;
  int skoff = (lane & 3) * 8;
  const __bf16* Abase = A + (size_t)(row0 + srow) * K + skoff;
  const __bf16* Bbase = Wt + (size_t)(n0 + srow) * K + skoff;
  for (int k0 = 0; k0 < K; k0 += 32) {
    __syncthreads();
#pragma unroll
    for (int cc = 0; cc < 3; ++cc) {
      int c = wid * 3 + cc;
      if (c < 4) GLOAD(Abase + (size_t)c * 16 * K + k0, As + c * 512);
      else       GLOAD(Bbase + (size_t)(c - 4) * 16 * K + k0, Bs + (c - 4) * 512);
    }
    __syncthreads();
    bf16x8 af[2], bfr[4];
#pragma unroll
    for (int i = 0; i < 2; ++i)
      af[i] = *(const bf16x8*)&As[(wr * 32 + i * 16 + (lane & 15)) * 32 + (lane >> 4) * 8];
#pragma unroll
    for (int j = 0; j < 4; ++j)
      bfr[j] = *(const bf16x8*)&Bs[(wc * 64 + j * 16 + (lane & 15)) * 32 + (lane >> 4) * 8];
#pragma unroll
    for (int i = 0; i < 2; ++i)
#pragma unroll
      for (int j = 0; j < 4; ++j)
        acc[i][j] = __builtin_amdgcn_mfma_f32_16x16x32_bf16(af[i], bfr[j], acc[i][j], 0, 0, 0);
  }
  int orow = row0 + wr * 32 + (lane >> 4) * 4;
  int ocol = n0 + wc * 64 + (lane & 15);
#pragma unroll
  for (int i = 0; i < 2; ++i)
#pragma unroll
    for (int j = 0; j < 4; ++j) {
      int col = ocol + j * 16;
      float bv = bias[col];
#pragma unroll
      for (int r = 0; r < 4; ++r) {
        int row = orow + i * 16 + r;
        float v = acc[i][j][r] + bv;
        if (RELU) v = fmaxf(v, 0.f);
        Cb[(size_t)row * N + col] = (__bf16)v;
      }
    }
}

// ---------------------------------------------------------------------------
// Fused [qproj|val] GEMM (128x128): bn<3 -> qproj fp32 (stride 384),
//                                    bn>=3 -> val bf16 (stride 256)
// ---------------------------------------------------------------------------
__global__ __launch_bounds__(256) void gemm_qv_kernel(
    const __bf16* __restrict__ qb, const __bf16* __restrict__ xb,
    const __bf16* __restrict__ Wt, const float* __restrict__ bias,
    float* __restrict__ qproj, __bf16* __restrict__ valb) {
  __shared__ __bf16 As[128 * 32];
  __shared__ __bf16 Bs[128 * 32];
  int t = threadIdx.x;
  int lane = t & 63, wid = t >> 6;
  int wr = wid >> 1, wc = wid & 1;
  int bn = blockIdx.x;                    // 0..4
  int row0 = blockIdx.y * 128;
  int n0 = bn * 128;
  const __bf16* A = (bn < 3) ? qb : xb;
  floatx4 acc[4][4] = {};
  int srow = lane >> 2;
  int skoff = (lane & 3) * 8;
  const __bf16* Abase = A + (size_t)(row0 + srow) * 256 + skoff;
  const __bf16* Bbase = Wt + (size_t)(n0 + srow) * 256 + skoff;
  GEMM_CORE(Abase, Bbase, 256)
  int orow = row0 + wr * 64 + (lane >> 4) * 4;
  int ocol = wc * 64 + (lane & 15);
#pragma unroll
  for (int i = 0; i < 4; ++i)
#pragma unroll
    for (int j = 0; j < 4; ++j) {
      int col = ocol + j * 16;
      float bv = bias[n0 + col];
#pragma unroll
      for (int r = 0; r < 4; ++r) {
        int row = orow + i * 16 + r;
        float v = acc[i][j][r] + bv;
        if (bn < 3) qproj[(size_t)row * 384 + n0 + col] = v;
        else        valb[(size_t)row * 256 + (n0 - 384) + col] = (__bf16)v;
      }
    }
}

// ---------------------------------------------------------------------------
// Deformable sampling + per-head softmax. 8 queries/block as a 4x2 spatial
// tile (y-adjacent corner reuse in L1), 32 threads/query, branchless clamped
// gathers (4x16B per point). Output bf16.
// Per batch: 672 blocks = 512 L0(64x64) + 128 L1(32x32) + 32 L2(16x16).
// ---------------------------------------------------------------------------
__global__ __launch_bounds__(256) void deform_kernel(
    const __bf16* __restrict__ val, const float* __restrict__ qproj,
    __bf16* __restrict__ out) {
  int bid = blockIdx.x;             // 0..2687
  int b = bid / 672, r = bid % 672;
  int j = threadIdx.x >> 5;         // query slot 0..7 (4x2 tile)
  int jx = j & 3, jy = j >> 2;
  int wsrc, qbase, px, py;
  if (r < 512)      { wsrc = 64; qbase = 0;    int ty = r >> 4, tx = r & 15;          px = tx * 4 + jx; py = ty * 2 + jy; }
  else if (r < 640) { wsrc = 32; qbase = 4096; int t = r - 512; int ty = t >> 3, tx = t & 7; px = tx * 4 + jx; py = ty * 2 + jy; }
  else              { wsrc = 16; qbase = 5120; int t = r - 640; int ty = t >> 2, tx = t & 3; px = tx * 4 + jx; py = ty * 2 + jy; }
  int q = qbase + py * wsrc + px;
  int bq = b * QTOT + q;
  int tq = threadIdx.x & 31;
  int hid = tq >> 2, dq = (tq & 3) * 8;

  float inv = 1.0f / (float)wsrc;
  float refx = ((float)px + 0.5f) * inv;
  float refy = ((float)py + 0.5f) * inv;

  const float* base = qproj + (size_t)bq * 384;
  float aw[12], ob[24];
  *(float4*)&aw[0] = *(const float4*)(base + 192 + hid * 12);
  *(float4*)&aw[4] = *(const float4*)(base + 192 + hid * 12 + 4);
  *(float4*)&aw[8] = *(const float4*)(base + 192 + hid * 12 + 8);
#pragma unroll
  for (int i = 0; i < 6; ++i)
    *(float4*)&ob[i * 4] = *(const float4*)(base + hid * 24 + i * 4);

  float mx = -1e30f;
#pragma unroll
  for (int k = 0; k < 12; ++k) mx = fmaxf(mx, aw[k]);
  float s = 0.f;
#pragma unroll
  for (int k = 0; k < 12; ++k) { aw[k] = __expf(aw[k] - mx); s += aw[k]; }
  float invs = 1.0f / s;
#pragma unroll
  for (int k = 0; k < 12; ++k) aw[k] *= invs;

  const __bf16* vb = val + ((size_t)b * QTOT) * DMODEL + hid * 32 + dq;

  const int starts[3] = {0, 4096, 5120};
  const int wls[3] = {64, 32, 16};
  float acc[8] = {};
#pragma unroll
  for (int l = 0; l < 3; ++l) {
    int wl = wls[l];
    float fwl = (float)wl;
    const __bf16* vlb = vb + (size_t)starts[l] * DMODEL;
#pragma unroll
    for (int pp = 0; pp < 4; ++pp) {
      float awp = aw[l * 4 + pp];
      float fx = refx * fwl + ob[(l * 4 + pp) * 2 + 0] - 0.5f;
      float fy = refy * fwl + ob[(l * 4 + pp) * 2 + 1] - 0.5f;
      float x0f = floorf(fx), y0f = floorf(fy);
      float lx = fx - x0f, ly = fy - y0f;
      int x0 = (int)x0f, y0 = (int)y0f;
      float wx0 = ((unsigned)x0 < (unsigned)wl) ? (1.f - lx) : 0.f;
      float wx1 = ((unsigned)(x0 + 1) < (unsigned)wl) ? lx : 0.f;
      float wy0 = (((unsigned)y0 < (unsigned)wl) ? (1.f - ly) : 0.f) * awp;
      float wy1 = (((unsigned)(y0 + 1) < (unsigned)wl) ? ly : 0.f) * awp;
      int xc0 = min(max(x0, 0), wl - 1);
      int xc1 = min(max(x0 + 1, 0), wl - 1);
      int yc0 = min(max(y0, 0), wl - 1);
      int yc1 = min(max(y0 + 1, 0), wl - 1);
      const __bf16* r0 = vlb + (size_t)(yc0 * wl) * DMODEL;
      const __bf16* r1 = vlb + (size_t)(yc1 * wl) * DMODEL;
      bf16x8 v00 = *(const bf16x8*)(r0 + (size_t)xc0 * DMODEL);
      bf16x8 v01 = *(const bf16x8*)(r0 + (size_t)xc1 * DMODEL);
      bf16x8 v10 = *(const bf16x8*)(r1 + (size_t)xc0 * DMODEL);
      bf16x8 v11 = *(const bf16x8*)(r1 + (size_t)xc1 * DMODEL);
      float w00 = wx0 * wy0, w01 = wx1 * wy0;
      float w10 = wx0 * wy1, w11 = wx1 * wy1;
#pragma unroll
      for (int e = 0; e < 8; ++e) {
        float v = w00 * (float)v00[e] + w01 * (float)v01[e] +
                  w10 * (float)v10[e] + w11 * (float)v11[e];
        acc[e] += v;
      }
    }
  }
  bf16x8 o;
#pragma unroll
  for (int e = 0; e < 8; ++e) o[e] = (__bf16)acc[e];
  *(bf16x8*)(out + (size_t)bq * DMODEL + hid * 32 + dq) = o;
}

// ---------------------------------------------------------------------------
// xout = LayerNorm(xin + res), all bf16 I/O (fp32 math). One wave per row.
// If QB: qb = bf16(out + posb). If fout != nullptr: also write fp32 out.
// ---------------------------------------------------------------------------
template<int QB>
__global__ __launch_bounds__(256) void add_ln_kernel(
    const __bf16* __restrict__ xin, const __bf16* __restrict__ res,
    const float* __restrict__ g, const float* __restrict__ bta,
    __bf16* __restrict__ xout, const __bf16* __restrict__ posb,
    __bf16* __restrict__ qb, float* __restrict__ fout) {
  int row = blockIdx.x * 4 + (threadIdx.x >> 6);
  int lane = threadIdx.x & 63;
  int c = lane * 4;
  bf16x4 xv4 = *(const bf16x4*)(xin + (size_t)row * DMODEL + c);
  bf16x4 rv4 = *(const bf16x4*)(res + (size_t)row * DMODEL + c);
  float xv0 = (float)xv4[0] + (float)rv4[0];
  float xv1 = (float)xv4[1] + (float)rv4[1];
  float xv2 = (float)xv4[2] + (float)rv4[2];
  float xv3 = (float)xv4[3] + (float)rv4[3];
  float s = xv0 + xv1 + xv2 + xv3;
  float sq = xv0 * xv0 + xv1 * xv1 + xv2 * xv2 + xv3 * xv3;
#pragma unroll
  for (int o = 32; o >= 1; o >>= 1) {
    s += __shfl_xor(s, o);
    sq += __shfl_xor(sq, o);
  }
  float mean = s * (1.f / 256.f);
  float var = sq * (1.f / 256.f) - mean * mean;
  float rstd = rsqrtf(var + 1e-5f);
  float4 gv = *(const float4*)(g + c);
  float4 bv = *(const float4*)(bta + c);
  float o0 = (xv0 - mean) * rstd * gv.x + bv.x;
  float o1 = (xv1 - mean) * rstd * gv.y + bv.y;
  float o2 = (xv2 - mean) * rstd * gv.z + bv.z;
  float o3 = (xv3 - mean) * rstd * gv.w + bv.w;
  bf16x4 ob;
  ob[0] = (__bf16)o0; ob[1] = (__bf16)o1;
  ob[2] = (__bf16)o2; ob[3] = (__bf16)o3;
  *(bf16x4*)(xout + (size_t)row * DMODEL + c) = ob;
  if (QB) {
    bf16x4 pv = *(const bf16x4*)(posb + (size_t)row * DMODEL + c);
    bf16x4 qv;
    qv[0] = (__bf16)(o0 + (float)pv[0]); qv[1] = (__bf16)(o1 + (float)pv[1]);
    qv[2] = (__bf16)(o2 + (float)pv[2]); qv[3] = (__bf16)(o3 + (float)pv[3]);
    *(bf16x4*)(qb + (size_t)row * DMODEL + c) = qv;
  }
  if (fout) {
    float4 f4 = make_float4(o0, o1, o2, o3);
    *(float4*)(fout + (size_t)row * DMODEL + c) = f4;
  }
}

// ---------------------------------------------------------------------------
extern "C" void kernel_launch(void* const* d_in, const int* in_sizes, int n_in,
                              void* d_out, int out_size, void* d_ws, size_t ws_size,
                              hipStream_t stream) {
  const float* src0 = (const float*)d_in[0];
  const float* pos0 = (const float*)d_in[1];
  const float* src1 = (const float*)d_in[2];
  const float* pos1 = (const float*)d_in[3];
  const float* src2 = (const float*)d_in[4];
  const float* pos2 = (const float*)d_in[5];
  const float* lvl  = (const float*)d_in[6];
  const float* W_off  = (const float*)d_in[7];
  const float* b_off  = (const float*)d_in[8];
  const float* W_attn = (const float*)d_in[9];
  const float* b_attn = (const float*)d_in[10];
  const float* W_val  = (const float*)d_in[11];
  const float* b_val  = (const float*)d_in[12];
  const float* W_out  = (const float*)d_in[13];
  const float* b_out  = (const float*)d_in[14];
  const float* ln1g = (const float*)d_in[15];
  const float* ln1b = (const float*)d_in[16];
  const float* W_ff1 = (const float*)d_in[17];
  const float* b_ff1 = (const float*)d_in[18];
  const float* W_ff2 = (const float*)d_in[19];
  const float* b_ff2 = (const float*)d_in[20];
  const float* ln2g = (const float*)d_in[21];
  const float* ln2b = (const float*)d_in[22];

  const size_t M = (size_t)MROWS;
  char* w = (char*)d_ws;
  __bf16* xb    = (__bf16*)w;                w += M * 256 * 2;
  __bf16* posb  = (__bf16*)w;                w += M * 256 * 2;
  __bf16* qb    = (__bf16*)w;                w += M * 256 * 2;   // alias: attn_bf
  float*  qproj = (float*)w;                 w += M * 384 * 4;   // alias: ffres(bf16)
  __bf16* valb  = (__bf16*)w;                w += M * 256 * 2;
  __bf16* ffh   = (__bf16*)w;                w += M * 1024 * 2;  // alias: proj(bf16)
  __bf16* wqv_t = (__bf16*)w;                w += (size_t)NLAYERS * 640 * 256 * 2;
  __bf16* wout_t= (__bf16*)w;                w += (size_t)NLAYERS * 256 * 256 * 2;
  __bf16* wff1_t= (__bf16*)w;                w += (size_t)NLAYERS * 1024 * 256 * 2;
  __bf16* wff2_t= (__bf16*)w;                w += (size_t)NLAYERS * 256 * 1024 * 2;
  float*  bqv   = (float*)w;                 w += (size_t)NLAYERS * 640 * 4;
  __bf16* attn_bf = qb;
  __bf16* proj  = ffh;           // consumed by LN1 before ffh is written
  __bf16* ffres = (__bf16*)qproj;

  pack_qv_t_kernel<<<dim3(20, 8, NLAYERS), 256, 0, stream>>>(W_off, W_attn, W_val, wqv_t);
  pack_bias_kernel<<<NLAYERS, 640, 0, stream>>>(b_off, b_attn, b_val, bqv);
  pack3_kernel<<<dim3(576, NLAYERS), 256, 0, stream>>>(
      W_out, W_ff1, W_ff2, wout_t, wff1_t, wff2_t);

  flatten_kernel<<<dim3(1344, BATCH), 256, 0, stream>>>(
      src0, pos0, src1, pos1, src2, pos2, lvl, xb, posb, qb);

  const int MT = MROWS / 128;   // 168
  const int MT64 = MROWS / 64;  // 336
  for (int i = 0; i < NLAYERS; ++i) {
    gemm_qv_kernel<<<dim3(5, MT), 256, 0, stream>>>(
        qb, xb, wqv_t + (size_t)i * 640 * 256, bqv + i * 640, qproj, valb);
    deform_kernel<<<MROWS / 8, 256, 0, stream>>>(valb, qproj, attn_bf);
    gemm64_bf16_kernel<0><<<dim3(2, MT64), 256, 0, stream>>>(
        attn_bf, wout_t + (size_t)i * 256 * 256, b_out + i * 256, proj, 256, 256);
    add_ln_kernel<0><<<MROWS / 4, 256, 0, stream>>>(
        xb, proj, ln1g + i * 256, ln1b + i * 256, xb, nullptr, nullptr, nullptr);
    gemm_bf16_kernel<1, 1><<<dim3(8, MT), 256, 0, stream>>>(
        xb, wff1_t + (size_t)i * 1024 * 256, b_ff1 + i * 1024, nullptr, ffh, 1024, 256);
    gemm64_bf16_kernel<0><<<dim3(2, MT64), 256, 0, stream>>>(
        ffh, wff2_t + (size_t)i * 256 * 1024, b_ff2 + i * 256, ffres, 256, 1024);
    float* fout = (i == NLAYERS - 1) ? (float*)d_out : nullptr;
    add_ln_kernel<1><<<MROWS / 4, 256, 0, stream>>>(
        xb, ffres, ln2g + i * 256, ln2b + i * 256, xb, posb, qb, fout);
  }
}